// Round 1
// baseline (6486.505 us; speedup 1.0000x reference)
//
#include <hip/hip_runtime.h>

// GPT-2 small forward on gfx950. bf16 MFMA GEMMs, fp32 residual stream.
// Layout notes (HW-verified per guide):
//   mfma_f32_16x16x32_bf16: A/B frag: elem j of lane L = M[L&15][(L>>4)*8+j]
//   C/D: reg r of lane L = C[(L>>4)*4 + r][L&15]

typedef __attribute__((ext_vector_type(4))) float f32x4;
typedef __attribute__((ext_vector_type(8))) short short8;
typedef __attribute__((ext_vector_type(4))) unsigned int u32x4;
typedef __attribute__((ext_vector_type(2))) unsigned int u32x2;

__device__ __forceinline__ float bf2f_u(unsigned int lo16){
  union { unsigned int i; float f; } v; v.i = lo16 << 16; return v.f;
}
__device__ __forceinline__ unsigned short f2bf(float x){
  union { float f; unsigned int i; } v; v.f = x;
  unsigned int i = v.i;
  return (unsigned short)((i + 0x7fffu + ((i >> 16) & 1u)) >> 16);
}
__device__ __forceinline__ int swz(int row){ return (row >> 1) & 3; }

// ---------------- embedding ----------------
__global__ __launch_bounds__(256) void embed_k(const int* __restrict__ ids,
    const float* __restrict__ wte, const float* __restrict__ wpe, float* __restrict__ x){
  int tok = blockIdx.x, t = threadIdx.x;
  int id = ids[tok]; int pos = tok & 1023;
  const float* we = wte + (size_t)id * 768;
  const float* pe = wpe + (size_t)pos * 768;
  float* xo = x + (size_t)tok * 768;
  #pragma unroll
  for (int j = 0; j < 3; j++){ int c = t + j*256; xo[c] = we[c] + pe[c]; }
}

// ---------------- layernorm -> bf16 ----------------
__global__ __launch_bounds__(256) void ln_k(const float* __restrict__ X,
    const float* __restrict__ g, const float* __restrict__ bta, unsigned short* __restrict__ H){
  int row = blockIdx.x, t = threadIdx.x;
  const float* xr = X + (size_t)row * 768;
  float v0 = xr[t], v1 = xr[t+256], v2 = xr[t+512];
  float s = v0+v1+v2;
  float ss = v0*v0+v1*v1+v2*v2;
  #pragma unroll
  for (int o = 32; o > 0; o >>= 1){ s += __shfl_xor(s, o, 64); ss += __shfl_xor(ss, o, 64); }
  __shared__ float rs_[4], rq_[4];
  int w = t >> 6;
  if ((t & 63) == 0){ rs_[w] = s; rq_[w] = ss; }
  __syncthreads();
  s  = rs_[0]+rs_[1]+rs_[2]+rs_[3];
  ss = rq_[0]+rq_[1]+rq_[2]+rq_[3];
  float mu = s * (1.f/768.f);
  float var = ss * (1.f/768.f) - mu*mu;
  float r = rsqrtf(var + 1e-5f);
  unsigned short* ho = H + (size_t)row*768;
  float vv[3] = {v0, v1, v2};
  #pragma unroll
  for (int j=0;j<3;j++){ int c = t + j*256; ho[c] = f2bf((vv[j] - mu)*r*g[c] + bta[c]); }
}

// ---------------- GEMM: C[M,N] = A(bf16)[M,K] @ B(f32) (+bias)(+gelu)(+resid) ----------------
// BL=0: B is [K,N] row-major.  BL=1: B is [N,K] row-major (lm_head, B=wte).
template<int TM, int BL, bool RESID, bool GELU_ACT, bool OUTBF16, bool NGUARD>
__global__ __launch_bounds__(256, 2) void gemm_k(
    const unsigned short* __restrict__ A, const float* __restrict__ Bw,
    const float* __restrict__ bias, const float* __restrict__ resid,
    void* __restrict__ Cp, int M, int N, int K)
{
  constexpr int BM = TM * 32;
  __shared__ __align__(16) unsigned short As[128*32];
  __shared__ __align__(16) unsigned short Bs[128*32];
  const int tid = threadIdx.x;
  const int m0 = blockIdx.x * BM, n0 = blockIdx.y * 128;
  const int lane = tid & 63, w = tid >> 6;
  const int quad = lane >> 4, lr = lane & 15;
  const int wm = (w >> 1) * (TM*16), wn = (w & 1) * 64;

  f32x4 acc[TM][4];
  #pragma unroll
  for (int i=0;i<TM;i++)
    #pragma unroll
    for (int j=0;j<4;j++) acc[i][j] = (f32x4)0.f;

  // staging registers
  u32x4 aReg[TM/2 > 0 ? TM/2 : 1];
  float bReg[16];
  const int kb = (tid >> 5) * 4;        // BL==0
  const int nn = (tid & 31) * 4;        // BL==0
  const int nr = tid >> 1;              // BL==1
  const int kk = (tid & 1) * 16;        // BL==1

  auto loadA = [&](int k0){
    #pragma unroll
    for (int j = 0; j < TM/2; j++){
      int idx = tid * (TM/2) + j;
      int row = idx >> 2, b = idx & 3;
      aReg[j] = *(const u32x4*)(A + (size_t)(m0+row)*K + k0 + b*8);
    }
  };
  auto loadB = [&](int k0){
    if (BL == 0){
      #pragma unroll
      for (int i=0;i<4;i++){
        f32x4 v = *(const f32x4*)(Bw + (size_t)(k0+kb+i)*N + n0 + nn);
        #pragma unroll
        for (int j=0;j<4;j++) bReg[i*4+j] = v[j];
      }
    } else {
      int gn = n0 + nr;
      if (!NGUARD || gn < N){
        #pragma unroll
        for (int q2=0;q2<4;q2++){
          f32x4 v = *(const f32x4*)(Bw + (size_t)gn*K + k0 + kk + q2*4);
          #pragma unroll
          for (int j=0;j<4;j++) bReg[q2*4+j] = v[j];
        }
      } else {
        #pragma unroll
        for (int q2=0;q2<16;q2++) bReg[q2] = 0.f;
      }
    }
  };
  auto storeA = [&](){
    #pragma unroll
    for (int j=0;j<TM/2;j++){
      int idx = tid*(TM/2)+j;
      int row = idx>>2, b = idx&3;
      int off = row*64 + ((b ^ swz(row))<<4);
      *(u32x4*)((char*)As + off) = aReg[j];
    }
  };
  auto storeB = [&](){
    if (BL == 0){
      int blk = kb >> 3;
      #pragma unroll
      for (int j=0;j<4;j++){
        int row = nn + j;
        unsigned int lo = (unsigned int)f2bf(bReg[0*4+j]) | ((unsigned int)f2bf(bReg[1*4+j]) << 16);
        unsigned int hi = (unsigned int)f2bf(bReg[2*4+j]) | ((unsigned int)f2bf(bReg[3*4+j]) << 16);
        int off = row*64 + ((blk ^ swz(row)) << 4) + (kb & 7)*2;
        u32x2 pv = {lo, hi};
        *(u32x2*)((char*)Bs + off) = pv;
      }
    } else {
      int row = nr;
      #pragma unroll
      for (int half=0; half<2; half++){
        unsigned int w0 = (unsigned int)f2bf(bReg[half*8+0]) | ((unsigned int)f2bf(bReg[half*8+1])<<16);
        unsigned int w1 = (unsigned int)f2bf(bReg[half*8+2]) | ((unsigned int)f2bf(bReg[half*8+3])<<16);
        unsigned int w2 = (unsigned int)f2bf(bReg[half*8+4]) | ((unsigned int)f2bf(bReg[half*8+5])<<16);
        unsigned int w3 = (unsigned int)f2bf(bReg[half*8+6]) | ((unsigned int)f2bf(bReg[half*8+7])<<16);
        int blk = (kk >> 3) + half;
        int off = row*64 + ((blk ^ swz(row)) << 4);
        u32x4 pv = {w0,w1,w2,w3};
        *(u32x4*)((char*)Bs + off) = pv;
      }
    }
  };

  loadA(0); loadB(0);
  const int nK = K / 32;
  for (int kt = 0; kt < nK; kt++){
    __syncthreads();
    storeA(); storeB();
    __syncthreads();
    if (kt + 1 < nK){ loadA((kt+1)*32); loadB((kt+1)*32); }
    short8 af[TM], bfr[4];
    #pragma unroll
    for (int i=0;i<TM;i++){
      int row = wm + i*16 + lr;
      af[i] = *(const short8*)((const char*)As + row*64 + ((quad ^ swz(row))<<4));
    }
    #pragma unroll
    for (int j=0;j<4;j++){
      int col = wn + j*16 + lr;
      bfr[j] = *(const short8*)((const char*)Bs + col*64 + ((quad ^ swz(col))<<4));
    }
    #pragma unroll
    for (int i=0;i<TM;i++)
      #pragma unroll
      for (int j=0;j<4;j++)
        acc[i][j] = __builtin_amdgcn_mfma_f32_16x16x32_bf16(af[i], bfr[j], acc[i][j], 0, 0, 0);
  }

  // epilogue
  #pragma unroll
  for (int i=0;i<TM;i++){
    #pragma unroll
    for (int j=0;j<4;j++){
      int col = n0 + wn + j*16 + lr;
      bool ok = !NGUARD || (col < N);
      float bv = 0.f;
      if (bias != nullptr && ok) bv = bias[col];
      #pragma unroll
      for (int r2=0;r2<4;r2++){
        int row = m0 + wm + i*16 + quad*4 + r2;
        float v = acc[i][j][r2] + bv;
        if (GELU_ACT){
          float x3 = v*v*v;
          v = 0.5f*v*(1.f + tanhf(0.7978845608028654f*(v + 0.044715f*x3)));
        }
        if (RESID && ok) v += resid[(size_t)row*N + col];
        if (ok){
          if (OUTBF16) ((unsigned short*)Cp)[(size_t)row*N + col] = f2bf(v);
          else         ((float*)Cp)[(size_t)row*N + col] = v;
        }
      }
    }
  }
}

// ---------------- causal attention (flash-style, fp32 vector) ----------------
// block = (b*12+h, qtile of 64 rows), 256 threads.
// thread: rq = tid&15 -> rows r0=rq*4..+3 ; dg = tid>>4 -> dims/keys d0=dg*4..+3
__global__ __launch_bounds__(256, 2) void attn_k(const unsigned short* __restrict__ qkv,
                                                 unsigned short* __restrict__ O){
  __shared__ __align__(16) float qsT[64*64];          // [d][row], q pre-scaled
  __shared__ __align__(16) float ksT[64*64];          // [d][key]
  __shared__ __align__(16) float psT[64*64];          // [key][row]
  __shared__ __align__(16) unsigned short vsm[64*72]; // [key][d] bf16
  const int bh = blockIdx.x, qt = blockIdx.y;
  const int b = bh / 12, h = bh % 12;
  const int tid = threadIdx.x;
  const int rq = tid & 15, dg = tid >> 4;
  const int r0 = rq * 4, d0 = dg * 4;
  const int tr = tid >> 2, c16 = (tid & 3) * 16;

  { // stage Q (scaled by 1/sqrt(64))
    const unsigned short* src = qkv + (size_t)(b*1024 + qt*64 + tr)*2304 + h*64 + c16;
    u32x4 u0 = *(const u32x4*)src;
    u32x4 u1 = *(const u32x4*)(src + 8);
    #pragma unroll
    for (int i=0;i<4;i++){
      qsT[(c16 + i*2 + 0)*64 + tr] = bf2f_u(u0[i] & 0xffffu) * 0.125f;
      qsT[(c16 + i*2 + 1)*64 + tr] = bf2f_u(u0[i] >> 16)     * 0.125f;
      qsT[(c16 + 8 + i*2 + 0)*64 + tr] = bf2f_u(u1[i] & 0xffffu) * 0.125f;
      qsT[(c16 + 8 + i*2 + 1)*64 + tr] = bf2f_u(u1[i] >> 16)     * 0.125f;
    }
  }

  f32x4 oacc[4];
  #pragma unroll
  for (int i=0;i<4;i++) oacc[i] = (f32x4)0.f;
  f32x4 m4 = (f32x4)(-1e30f);
  f32x4 l4 = (f32x4)0.f;

  for (int kt = 0; kt <= qt; kt++){
    __syncthreads();
    { // stage K (transposed, f32) and V (bf16 raw copy)
      const unsigned short* ks_ = qkv + (size_t)(b*1024 + kt*64 + tr)*2304 + 768 + h*64 + c16;
      u32x4 k0 = *(const u32x4*)ks_;
      u32x4 k1 = *(const u32x4*)(ks_ + 8);
      #pragma unroll
      for (int i=0;i<4;i++){
        ksT[(c16 + i*2 + 0)*64 + tr] = bf2f_u(k0[i] & 0xffffu);
        ksT[(c16 + i*2 + 1)*64 + tr] = bf2f_u(k0[i] >> 16);
        ksT[(c16 + 8 + i*2 + 0)*64 + tr] = bf2f_u(k1[i] & 0xffffu);
        ksT[(c16 + 8 + i*2 + 1)*64 + tr] = bf2f_u(k1[i] >> 16);
      }
      const unsigned short* vs_ = ks_ + 768;
      u32x4 v0 = *(const u32x4*)vs_;
      u32x4 v1 = *(const u32x4*)(vs_ + 8);
      *(u32x4*)&vsm[tr*72 + c16] = v0;
      *(u32x4*)&vsm[tr*72 + c16 + 8] = v1;
    }
    __syncthreads();

    // scores: s_j[i] = q[r0+i] . k[d0+j]
    f32x4 s0=(f32x4)0.f, s1=(f32x4)0.f, s2=(f32x4)0.f, s3=(f32x4)0.f;
    #pragma unroll 4
    for (int d=0; d<64; d++){
      f32x4 qv = *(const f32x4*)&qsT[d*64 + r0];
      float ka = ksT[d*64 + d0+0];
      float kbb = ksT[d*64 + d0+1];
      float kc = ksT[d*64 + d0+2];
      float kd = ksT[d*64 + d0+3];
      s0 += qv * ka; s1 += qv * kbb; s2 += qv * kc; s3 += qv * kd;
    }
    if (kt == qt){
      #pragma unroll
      for (int i=0;i<4;i++){
        int qg = r0 + i;
        if (d0+0 > qg) s0[i] = -1e30f;
        if (d0+1 > qg) s1[i] = -1e30f;
        if (d0+2 > qg) s2[i] = -1e30f;
        if (d0+3 > qg) s3[i] = -1e30f;
      }
    }
    *(f32x4*)&psT[(d0+0)*64 + r0] = s0;
    *(f32x4*)&psT[(d0+1)*64 + r0] = s1;
    *(f32x4*)&psT[(d0+2)*64 + r0] = s2;
    *(f32x4*)&psT[(d0+3)*64 + r0] = s3;
    __syncthreads();

    // per-row tile max
    f32x4 rm = (f32x4)(-1e30f);
    for (int k=0;k<64;k++){
      f32x4 pv = *(const f32x4*)&psT[k*64 + r0];
      #pragma unroll
      for (int i=0;i<4;i++) rm[i] = fmaxf(rm[i], pv[i]);
    }
    f32x4 mnew, alpha;
    #pragma unroll
    for (int i=0;i<4;i++){
      mnew[i] = fmaxf(m4[i], rm[i]);
      alpha[i] = __expf(m4[i] - mnew[i]);
    }
    m4 = mnew;
    #pragma unroll
    for (int i=0;i<4;i++){ l4[i] *= alpha[i]; oacc[i] *= alpha[i]; }
    __syncthreads();  // all raw-score reads complete before overwrite

    // p = exp(s - mnew), write back
    #pragma unroll
    for (int i=0;i<4;i++){
      s0[i] = __expf(s0[i]-mnew[i]);
      s1[i] = __expf(s1[i]-mnew[i]);
      s2[i] = __expf(s2[i]-mnew[i]);
      s3[i] = __expf(s3[i]-mnew[i]);
    }
    *(f32x4*)&psT[(d0+0)*64 + r0] = s0;
    *(f32x4*)&psT[(d0+1)*64 + r0] = s1;
    *(f32x4*)&psT[(d0+2)*64 + r0] = s2;
    *(f32x4*)&psT[(d0+3)*64 + r0] = s3;
    __syncthreads();

    // PV: oacc[i][j] += p[k][i] * v[k][j], l += p
    for (int k=0;k<64;k++){
      f32x4 pv = *(const f32x4*)&psT[k*64 + r0];
      u32x2 vr = *(const u32x2*)&vsm[k*72 + d0];
      f32x4 vv;
      vv[0]=bf2f_u(vr[0]&0xffffu); vv[1]=bf2f_u(vr[0]>>16);
      vv[2]=bf2f_u(vr[1]&0xffffu); vv[3]=bf2f_u(vr[1]>>16);
      l4 += pv;
      #pragma unroll
      for (int i=0;i<4;i++) oacc[i] += vv * pv[i];
    }
  }

  #pragma unroll
  for (int i=0;i<4;i++){
    float inv = 1.f / l4[i];
    size_t base = (size_t)(b*1024 + qt*64 + r0 + i)*768 + h*64 + d0;
    unsigned int lo = (unsigned int)f2bf(oacc[i][0]*inv) | ((unsigned int)f2bf(oacc[i][1]*inv)<<16);
    unsigned int hi = (unsigned int)f2bf(oacc[i][2]*inv) | ((unsigned int)f2bf(oacc[i][3]*inv)<<16);
    u32x2 pv = {lo, hi};
    *(u32x2*)(O + base) = pv;
  }
}

// ---------------- launch ----------------
extern "C" void kernel_launch(void* const* d_in, const int* in_sizes, int n_in,
                              void* d_out, int out_size, void* d_ws, size_t ws_size,
                              hipStream_t stream) {
  const int*   ids    = (const int*)  d_in[0];
  const float* wte    = (const float*)d_in[1];
  const float* wpe    = (const float*)d_in[2];
  const float* ln1_g  = (const float*)d_in[3];
  const float* ln1_b  = (const float*)d_in[4];
  const float* w_attn = (const float*)d_in[5];
  const float* b_attn = (const float*)d_in[6];
  const float* w_proj = (const float*)d_in[7];
  const float* b_proj = (const float*)d_in[8];
  const float* ln2_g  = (const float*)d_in[9];
  const float* ln2_b  = (const float*)d_in[10];
  const float* w_fc   = (const float*)d_in[11];
  const float* b_fc   = (const float*)d_in[12];
  const float* w_mprj = (const float*)d_in[13];
  const float* b_mprj = (const float*)d_in[14];
  const float* lnf_g  = (const float*)d_in[15];
  const float* lnf_b  = (const float*)d_in[16];

  char* ws = (char*)d_ws;
  size_t off = 0;
  float*          x    = (float*)(ws + off);          off += (size_t)4096*768*4;
  unsigned short* h    = (unsigned short*)(ws + off); off += (size_t)4096*768*2;
  unsigned short* qkvb = (unsigned short*)(ws + off); off += (size_t)4096*2304*2;
  unsigned short* ob   = (unsigned short*)(ws + off); off += (size_t)4096*768*2;
  unsigned short* mid  = (unsigned short*)(ws + off); off += (size_t)4096*3072*2;
  if (ws_size < off) return;  // workspace too small -> fail loudly via poisoned output

  embed_k<<<4096, 256, 0, stream>>>(ids, wte, wpe, x);

  for (int l = 0; l < 12; l++){
    ln_k<<<4096, 256, 0, stream>>>(x, ln1_g + l*768, ln1_b + l*768, h);
    gemm_k<4,0,false,false,true,false><<<dim3(32,18), 256, 0, stream>>>(
        h, w_attn + (size_t)l*768*2304, b_attn + l*2304, nullptr, qkvb, 4096, 2304, 768);
    attn_k<<<dim3(48,16), 256, 0, stream>>>(qkvb, ob);
    gemm_k<2,0,true,false,false,false><<<dim3(64,6), 256, 0, stream>>>(
        ob, w_proj + (size_t)l*768*768, b_proj + l*768, x, x, 4096, 768, 768);
    ln_k<<<4096, 256, 0, stream>>>(x, ln2_g + l*768, ln2_b + l*768, h);
    gemm_k<4,0,false,true,true,false><<<dim3(32,24), 256, 0, stream>>>(
        h, w_fc + (size_t)l*768*3072, b_fc + l*3072, nullptr, mid, 4096, 3072, 768);
    gemm_k<2,0,true,false,false,false><<<dim3(64,6), 256, 0, stream>>>(
        mid, w_mprj + (size_t)l*3072*768, b_mprj + l*768, x, x, 4096, 768, 3072);
  }

  ln_k<<<4096, 256, 0, stream>>>(x, lnf_g, lnf_b, h);
  gemm_k<4,1,false,false,false,true><<<dim3(32,393), 256, 0, stream>>>(
      h, wte, nullptr, nullptr, (float*)d_out, 4096, 50257, 768);
}